// Round 2
// 282.732 us; speedup vs baseline: 1.0203x; 1.0203x over previous
//
#include <hip/hip_runtime.h>
#include <math.h>

// Problem constants (match reference)
constexpr int N_ROWS = 100000;   // outputSize
constexpr int D      = 128;      // feature dim
constexpr int B      = 128;      // batch
constexpr int KP1    = 4097;     // K+1
constexpr int TOTAL_PAIRS = B * KP1;            // 524,416
constexpr float INV_T = 1.0f / 0.07f;
constexpr int N4 = N_ROWS * (D / 4);            // float4 per bank: 3.2M

constexpr int SC_BLOCKS = 1024;  // score blocks (even blockIdx)
constexpr int CP_BLOCKS = 1024;  // copy  blocks (odd blockIdx)

typedef float fvec4 __attribute__((ext_vector_type(4)));  // nontemporal-store-safe

// ---------------------------------------------------------------------------
__global__ void init_ws_kernel(float* ws) {
    if (threadIdx.x < 2) ws[threadIdx.x] = 0.0f;
}

__device__ __forceinline__ float dot4(float4 a, float4 b) {
    return a.x * b.x + a.y * b.y + a.z * b.z + a.w * b.w;
}

// xor-butterfly over the 32-lane group: leaves the full sum in ALL lanes
__device__ __forceinline__ float red32(float v) {
    #pragma unroll
    for (int off = 16; off >= 1; off >>= 1) v += __shfl_xor(v, off);
    return v;
}

// ---------------------------------------------------------------------------
// Even blocks: score. 8 blocks per b; each block owns a contiguous 512-wide
// k-chunk, preloads its idx slice into LDS, then each 32-lane group walks 64
// consecutive k's unrolled x4 (8 row-gathers in flight). Butterfly reduce
// leaves sums in all lanes -> redundant exp (no divergent epilogue), 4-wide
// coalesced stores by lanes 0-3 (out_v1) and 4-7 (out_v2).
// Odd blocks: stream-copy both banks to the output regions with nontemporal
// stores (the copied data is never re-read; keep L2 for the gathers).
__global__ __launch_bounds__(256) void mega_kernel(
    const float* __restrict__ v1, const float* __restrict__ v2,
    const int* __restrict__ idx,
    const float* __restrict__ mem1, const float* __restrict__ mem2,
    float* __restrict__ out,          // [0:T) unnorm out_v1, [T:2T) unnorm out_v2
    float* __restrict__ sums,         // ws: 2 floats
    float* __restrict__ o1, float* __restrict__ o2)
{
    if (blockIdx.x & 1) {
        // ---- copy half ----
        int cid = blockIdx.x >> 1;                    // 0..CP_BLOCKS-1
        const fvec4* __restrict__ m1 = (const fvec4*)mem1;
        const fvec4* __restrict__ m2 = (const fvec4*)mem2;
        fvec4* __restrict__ d1 = (fvec4*)o1;
        fvec4* __restrict__ d2 = (fvec4*)o2;
        int tid = cid * 256 + threadIdx.x;
        int stride = CP_BLOCKS * 256;
        for (int i = tid; i < N4; i += stride) {
            fvec4 x1 = m1[i];
            fvec4 x2 = m2[i];
            __builtin_nontemporal_store(x1, &d1[i]);
            __builtin_nontemporal_store(x2, &d2[i]);
        }
        return;
    }

    // ---- score half ----
    __shared__ alignas(16) int s_idx[516];            // 513 used (chunk 7)
    __shared__ float s1[8], s2[8];

    const int sid   = blockIdx.x >> 1;                // 0..1023
    const int tid   = threadIdx.x;
    const int l     = tid & 31;                       // lane in 32-lane group
    const int grp   = tid >> 5;                       // 0..7
    const int b     = sid >> 3;                       // 8 blocks per b
    const int chunk = sid & 7;                        // which 512-wide k chunk
    const int cnt   = (chunk == 7) ? 513 : 512;       // chunk 7 also owns k=4096
    const int ibase = b * KP1 + chunk * 512;

    // coalesced one-shot preload of this block's idx slice
    for (int t = tid; t < cnt; t += 256) s_idx[t] = idx[ibase + t];
    __syncthreads();

    const float4* __restrict__ m1 = (const float4*)mem1;
    const float4* __restrict__ m2 = (const float4*)mem2;
    const float4 a1 = ((const float4*)v1)[b * 32 + l];
    const float4 a2 = ((const float4*)v2)[b * 32 + l];

    const int lk    = grp * 64;                       // group's local k offset
    const int pbase = ibase + lk;                     // global pair index base

    float acc1 = 0.0f, acc2 = 0.0f;                   // identical across lanes

    for (int u = 0; u < 64; u += 4) {
        // 4 indices in one ds_read_b128 (uniform address, broadcast)
        const int4 rr = *(const int4*)&s_idx[lk + u];

        // issue all 8 row-gathers back-to-back (8 x 512B in flight)
        float4 wA0 = m2[(size_t)rr.x * 32 + l];       // out_v1 = mem2 . v1
        float4 wB0 = m1[(size_t)rr.x * 32 + l];       // out_v2 = mem1 . v2
        float4 wA1 = m2[(size_t)rr.y * 32 + l];
        float4 wB1 = m1[(size_t)rr.y * 32 + l];
        float4 wA2 = m2[(size_t)rr.z * 32 + l];
        float4 wB2 = m1[(size_t)rr.z * 32 + l];
        float4 wA3 = m2[(size_t)rr.w * 32 + l];
        float4 wB3 = m1[(size_t)rr.w * 32 + l];

        // 8 independent reductions interleave their shuffle latency
        float dA0 = red32(dot4(wA0, a1));
        float dB0 = red32(dot4(wB0, a2));
        float dA1 = red32(dot4(wA1, a1));
        float dB1 = red32(dot4(wB1, a2));
        float dA2 = red32(dot4(wA2, a1));
        float dB2 = red32(dot4(wB2, a2));
        float dA3 = red32(dot4(wA3, a1));
        float dB3 = red32(dot4(wB3, a2));

        // all lanes compute exp (no divergence; results uniform in group)
        float eA0 = __expf(dA0 * INV_T);
        float eB0 = __expf(dB0 * INV_T);
        float eA1 = __expf(dA1 * INV_T);
        float eB1 = __expf(dB1 * INV_T);
        float eA2 = __expf(dA2 * INV_T);
        float eB2 = __expf(dB2 * INV_T);
        float eA3 = __expf(dA3 * INV_T);
        float eB3 = __expf(dB3 * INV_T);

        acc1 += (eA0 + eA1) + (eA2 + eA3);
        acc2 += (eB0 + eB1) + (eB2 + eB3);

        // lanes 0-3 store out_v1[k..k+3], lanes 4-7 store out_v2[k..k+3]
        float sa  = (l & 1) ? eA1 : eA0;
        float sb  = (l & 1) ? eA3 : eA2;
        float evA = (l & 2) ? sb : sa;
        float sc  = (l & 1) ? eB1 : eB0;
        float sd  = (l & 1) ? eB3 : eB2;
        float evB = (l & 2) ? sd : sc;
        int p = pbase + u;
        if (l < 4)      out[p + l] = evA;
        else if (l < 8) out[TOTAL_PAIRS + p + (l - 4)] = evB;
    }

    // tail pair k = 4096 (one group per b)
    if (chunk == 7 && grp == 7) {
        int r = s_idx[512];
        float4 wA = m2[(size_t)r * 32 + l];
        float4 wB = m1[(size_t)r * 32 + l];
        float dA = red32(dot4(wA, a1));
        float dB = red32(dot4(wB, a2));
        float eA = __expf(dA * INV_T);
        float eB = __expf(dB * INV_T);
        acc1 += eA;
        acc2 += eB;
        if (l == 0) {
            out[b * KP1 + 4096]               = eA;
            out[TOTAL_PAIRS + b * KP1 + 4096] = eB;
        }
    }

    // block reduction -> one atomic per block per accumulator
    if (l == 0) { s1[grp] = acc1; s2[grp] = acc2; }
    __syncthreads();
    if (tid == 0) {
        float t1 = 0.0f, t2 = 0.0f;
        #pragma unroll
        for (int i = 0; i < 8; ++i) { t1 += s1[i]; t2 += s2[i]; }
        atomicAdd(&sums[0], t1);
        atomicAdd(&sums[1], t2);
    }
}

// ---------------------------------------------------------------------------
// Scale scores by 1/Z and overwrite the y-rows of the copied banks with
// normalize(0.5*mem + 0.5*v). Runs after mega_kernel (stream-ordered).
__global__ __launch_bounds__(256) void finish_kernel(
    float* __restrict__ out, const float* __restrict__ sums,
    const float* __restrict__ v1, const float* __restrict__ v2,
    const int* __restrict__ y,
    const float* __restrict__ mem1, const float* __restrict__ mem2,
    float* __restrict__ o1, float* __restrict__ o2)
{
    // row updates: blocks 0..255, wave 0 of each
    if (blockIdx.x < 2 * B && threadIdx.x < 64) {
        int b    = blockIdx.x & (B - 1);
        int bank = blockIdx.x >> 7;
        int lane = threadIdx.x;
        const float2* __restrict__ m = (const float2*)(bank ? mem2 : mem1);
        const float2* __restrict__ v = (const float2*)(bank ? v2 : v1);
        float2* __restrict__ o       = (float2*)(bank ? o2 : o1);
        int row = y[b];
        float2 mv = m[(size_t)row * 64 + lane];
        float2 vv = v[b * 64 + lane];
        float2 u;
        u.x = 0.5f * mv.x + 0.5f * vv.x;
        u.y = 0.5f * mv.y + 0.5f * vv.y;
        float ss = u.x * u.x + u.y * u.y;
        #pragma unroll
        for (int off = 32; off >= 1; off >>= 1) ss += __shfl_xor(ss, off);
        float inv = 1.0f / sqrtf(ss);
        float2 r; r.x = u.x * inv; r.y = u.y * inv;
        o[(size_t)row * 64 + lane] = r;
    }

    // scale: grid-stride over both score regions
    float sc1 = (float)((double)TOTAL_PAIRS / ((double)sums[0] * (double)N_ROWS));
    float sc2 = (float)((double)TOTAL_PAIRS / ((double)sums[1] * (double)N_ROWS));
    int stride = gridDim.x * blockDim.x;
    for (int i = blockIdx.x * blockDim.x + threadIdx.x; i < 2 * TOTAL_PAIRS;
         i += stride) {
        out[i] *= (i < TOTAL_PAIRS) ? sc1 : sc2;
    }
}

// ---------------------------------------------------------------------------
extern "C" void kernel_launch(void* const* d_in, const int* in_sizes, int n_in,
                              void* d_out, int out_size, void* d_ws, size_t ws_size,
                              hipStream_t stream) {
    const float* v1   = (const float*)d_in[0];
    const float* v2   = (const float*)d_in[1];
    const int*   idx  = (const int*)d_in[2];
    const int*   y    = (const int*)d_in[3];
    const float* mem1 = (const float*)d_in[4];
    const float* mem2 = (const float*)d_in[5];

    float* out = (float*)d_out;
    float* out_mem1 = out + 2 * (size_t)TOTAL_PAIRS;
    float* out_mem2 = out_mem1 + (size_t)N_ROWS * D;
    float* sums = (float*)d_ws;

    init_ws_kernel<<<1, 64, 0, stream>>>(sums);

    mega_kernel<<<SC_BLOCKS + CP_BLOCKS, 256, 0, stream>>>(
        v1, v2, idx, mem1, mem2, out, sums, out_mem1, out_mem2);

    finish_kernel<<<1024, 256, 0, stream>>>(
        out, sums, v1, v2, y, mem1, mem2, out_mem1, out_mem2);
}